// Round 6
// baseline (92.309 us; speedup 1.0000x reference)
//
#include <hip/hip_runtime.h>
#include <stdint.h>

typedef unsigned short ushort_t;
typedef __attribute__((ext_vector_type(8))) short short8;
typedef __attribute__((ext_vector_type(4))) float f32x4;
typedef __attribute__((ext_vector_type(4))) unsigned int u32x4;

#define TOK  16384
#define DIM  512
#define NPAIR 64          // pmin*8+pmax, only pmin<pmax used (28 live bins)
#define MAXTILES 156      // sum ceil(cnt/128) <= 128 + 28

// ---- helpers ----
__device__ __forceinline__ unsigned short f2bf(float f) {  // RNE f32->bf16
  union { float f; uint32_t u; } v; v.f = f;
  uint32_t u = v.u;
  uint32_t r = (u + 0x7fffu + ((u >> 16) & 1u)) >> 16;
  return (unsigned short)r;
}

// ---- kernel 1 (merged): z<10 -> W transpose+cvt; z==10 -> router ----
__global__ void k_prep(const float* __restrict__ wspec, const float* __restrict__ wsh,
                       ushort_t* __restrict__ wt,
                       const float* __restrict__ sl, const float* __restrict__ shl,
                       float* __restrict__ w4, int* __restrict__ pairid,
                       int* __restrict__ cnt) {
  if (blockIdx.z < 10) {
    // W[e][d][f] fp32 -> Wt[e][f][d] bf16
    __shared__ float t[32][33];
    int e = blockIdx.z;
    const float* src = (e < 8) ? (wspec + e * DIM * DIM) : (wsh + (e - 8) * DIM * DIM);
    int tx = threadIdx.x, ty = threadIdx.y;
    int d = blockIdx.y * 32 + ty, f = blockIdx.x * 32 + tx;
    t[ty][tx] = src[d * DIM + f];
    __syncthreads();
    int fo = blockIdx.x * 32 + ty, dd = blockIdx.y * 32 + tx;
    wt[(size_t)e * DIM * DIM + fo * DIM + dd] = f2bf(t[tx][ty]);
    return;
  }
  // router: 16 blocks x 1024 threads
  int blk = blockIdx.y * 16 + blockIdx.x;
  if (blk >= 16) return;
  __shared__ int h[NPAIR];
  int tid = threadIdx.y * 32 + threadIdx.x;
  int n = blk * 1024 + tid;
  if (tid < NPAIR) h[tid] = 0;
  __syncthreads();
  float l[8];
  float m = -1e30f;
#pragma unroll
  for (int i = 0; i < 8; ++i) { l[i] = sl[n*8 + i]; m = fmaxf(m, l[i]); }
  float s = 0.f;
#pragma unroll
  for (int i = 0; i < 8; ++i) { l[i] = expf(l[i] - m); s += l[i]; }
  float inv = 1.f / s;
#pragma unroll
  for (int i = 0; i < 8; ++i) l[i] *= inv;
  int i1 = 0; float v1 = l[0];
#pragma unroll
  for (int i = 1; i < 8; ++i) if (l[i] > v1) { v1 = l[i]; i1 = i; }
  int i2 = -1; float v2 = -1.f;
#pragma unroll
  for (int i = 0; i < 8; ++i) if (i != i1 && l[i] > v2) { v2 = l[i]; i2 = i; }
  float rs = 1.f / (v1 + v2 + 1e-6f);
  float w1 = v1 * rs, w2 = v2 * rs;
  int pmin, pmax; float wa, wb;
  if (i1 < i2) { pmin = i1; pmax = i2; wa = w1; wb = w2; }
  else         { pmin = i2; pmax = i1; wa = w2; wb = w1; }
  float s0 = shl[n*2], s1 = shl[n*2 + 1];
  float mm = fmaxf(s0, s1);
  float e0 = expf(s0 - mm), e1 = expf(s1 - mm);
  float si = 1.f / (e0 + e1);
  w4[n*4 + 0] = wa;
  w4[n*4 + 1] = wb;
  w4[n*4 + 2] = e0 * si;
  w4[n*4 + 3] = e1 * si;
  int p = pmin * 8 + pmax;
  pairid[n] = p;
  atomicAdd(&h[p], 1);                 // LDS atomic
  __syncthreads();
  if (tid < NPAIR && h[tid]) atomicAdd(&cnt[tid], h[tid]);  // <=16 per address
}

// ---- kernel 2: single-wave scan over 64 bins -> off/cursor/tileinfo ----
__global__ void k_scan(const int* __restrict__ cnt, int* __restrict__ off,
                       int* __restrict__ cursor, int* __restrict__ tsinfo,
                       int* __restrict__ tileinfo, ushort_t* __restrict__ idx) {
  int l = threadIdx.x;  // 64 threads = 1 wave
  int c = cnt[l];
  int t = (c + 127) >> 7;
  int sc = c, st = t;
#pragma unroll
  for (int d = 1; d < 64; d <<= 1) {
    int vc = __shfl_up(sc, d, 64);
    int vt = __shfl_up(st, d, 64);
    if (l >= d) { sc += vc; st += vt; }
  }
  int offv = sc - c, tsv = st - t;
  off[l] = offv; cursor[l] = offv;
  if (l == 63) tsinfo[64] = st;               // total row-tiles
  for (int q = 0; q < t; ++q) tileinfo[tsv + q] = (l << 16) | q;  // (pair, tstart)
  for (int i = l; i < 128; i += 64) idx[TOK + i] = 0;  // pad tail
}

// ---- kernel 3: fill packed token index (block-aggregated reservation) ----
__global__ void k_fill(const int* __restrict__ pairid, int* __restrict__ cursor,
                       ushort_t* __restrict__ idx) {
  __shared__ int hcnt[NPAIR];
  __shared__ int hbase[NPAIR];
  int tid = threadIdx.x;
  int n = blockIdx.x * 256 + tid;
  if (tid < NPAIR) hcnt[tid] = 0;
  __syncthreads();
  int p = pairid[n];
  int r = atomicAdd(&hcnt[p], 1);      // LDS atomic
  __syncthreads();
  if (tid < NPAIR && hcnt[tid]) hbase[tid] = atomicAdd(&cursor[tid], hcnt[tid]);
  __syncthreads();
  idx[hbase[p] + r] = (ushort_t)n;
}

// ---- kernel 4: fused gather + fp32->bf16 pack: xg[slot] = bf16(x[idx[slot]]) ----
__global__ void k_gather(const float* __restrict__ x, const ushort_t* __restrict__ idx,
                         ushort_t* __restrict__ xg) {
  int row = blockIdx.x * 4 + (threadIdx.x >> 6);
  int lane = threadIdx.x & 63;
  int t = (int)idx[row];
  const float* src = x + (size_t)t * DIM + lane * 8;
  f32x4 v0 = *(const f32x4*)src;
  f32x4 v1 = *(const f32x4*)(src + 4);
  u32x4 o;
  o[0] = (uint32_t)f2bf(v0[0]) | ((uint32_t)f2bf(v0[1]) << 16);
  o[1] = (uint32_t)f2bf(v0[2]) | ((uint32_t)f2bf(v0[3]) << 16);
  o[2] = (uint32_t)f2bf(v1[0]) | ((uint32_t)f2bf(v1[1]) << 16);
  o[3] = (uint32_t)f2bf(v1[2]) | ((uint32_t)f2bf(v1[3]) << 16);
  *(u32x4*)(xg + (size_t)row * DIM + lane * 8) = o;
}

// ---- kernel 5: pair-grouped sparse MoE GEMM ----
// Block = 128 packed rows x 64 cols, 4 waves (wave tile 64x32), BK=64.
// Grid = MAXTILES x 8 col-strips; cdx = bx&7 (== XCD id) so each XCD's B
// working set is 656 KB -> L2-resident. Loop s = ks*4 + j (32 steps): A staged
// once per ks (reused 4 experts), B every step; single-buffered, 2 barriers per
// step; 4-5 resident blocks/CU provide the cross-block latency hiding.
// ONE accumulator via cyclic telescoping: after phase j, acc *= w_j/w_{(j+1)&3}.
__global__ __launch_bounds__(256, 5)
void k_moe(const ushort_t* __restrict__ xg, const ushort_t* __restrict__ wt,
           const float* __restrict__ w4, const ushort_t* __restrict__ idx,
           const int* __restrict__ off, const int* __restrict__ cnt,
           const int* __restrict__ tsinfo, const int* __restrict__ tileinfo,
           const float* __restrict__ bspec, const float* __restrict__ bsh,
           float* __restrict__ out) {
  __shared__ ushort_t aB[8192];     // 16KB: 128 rows x 64k bf16, XOR-swizzled
  __shared__ ushort_t bB[4096];     // 8KB:  64 cols x 64k bf16
  __shared__ float wLT[4 * 128];    // w_j[row] (pad rows = 1.0)
  __shared__ float wRT[4 * 128];    // w_j[row]/w_{(j+1)&3}[row]
  __shared__ float bL[4 * 64];      // bias slice per phase

  const int tid  = threadIdx.x;
  const int lane = tid & 63;
  const int w    = tid >> 6;        // 0..3
  const int wr   = w >> 1, wc = w & 1;

  // cdx = XCD id; consecutive bx share the row-tile r
  int bx  = blockIdx.x;
  int r   = bx >> 3, cdx = bx & 7;
  if (r >= tsinfo[64]) return;
  int info = tileinfo[r];
  int p = info >> 16, tstart = info & 0xffff;
  const int base = off[p] + (tstart << 7);
  int cl = cnt[p] - (tstart << 7); if (cl > 128) cl = 128;
  const int e0 = p >> 3, e1 = p & 7;
  const int tcol = cdx << 6;

  // staging source offsets: invert the 16B-slot XOR swizzle at the source
  int soffA[4], soffB[2];
#pragma unroll
  for (int q = 0; q < 4; ++q) {
    int pp  = (q << 12) + tid * 16;       // byte in 16KB buffer
    int row = pp >> 7;                    // 0..127
    int kb  = (pp & 127) ^ ((row & 7) << 4);
    soffA[q] = row * DIM + (kb >> 1);
    if (q < 2) soffB[q] = soffA[q];       // same formula, rows 0..63
  }
  const ushort_t* aSrc = xg + (size_t)base * DIM;
  const ushort_t* bSrc = wt + (size_t)tcol * DIM;

  // meta: weights, telescoping ratios, bias
  for (int i = tid; i < 512; i += 256) {
    int j = i >> 7, rs = i & 127;
    float wa = 1.f, wb = 1.f;
    if (rs < cl) {
      int t = (int)idx[base + rs];
      wa = w4[t * 4 + j];
      wb = w4[t * 4 + ((j + 1) & 3)];
    }
    wLT[i] = wa;
    wRT[i] = wa / wb;
  }
  if (tid < 256) {
    int j = tid >> 6, col = tid & 63;
    int e = (j == 0) ? e0 : (j == 1) ? e1 : (j == 2) ? 8 : 9;
    bL[tid] = (e < 8) ? bspec[e * DIM + tcol + col] : bsh[(e - 8) * DIM + tcol + col];
  }

  // swizzled LDS read offsets (bytes)
  int aRd[4][2], bRd[2][2];
#pragma unroll
  for (int i = 0; i < 4; ++i) {
    int row = wr * 64 + i * 16 + (lane & 15);
#pragma unroll
    for (int ksl = 0; ksl < 2; ++ksl) {
      int kb = ((ksl << 6) + ((lane >> 4) << 4)) ^ ((row & 7) << 4);
      aRd[i][ksl] = row * 128 + kb;
    }
  }
#pragma unroll
  for (int i = 0; i < 2; ++i) {
    int col = wc * 32 + i * 16 + (lane & 15);
#pragma unroll
    for (int ksl = 0; ksl < 2; ++ksl) {
      int kb = ((ksl << 6) + ((lane >> 4) << 4)) ^ ((col & 7) << 4);
      bRd[i][ksl] = col * 128 + kb;
    }
  }

  f32x4 acc[4][2];
#pragma unroll
  for (int a = 0; a < 4; ++a)
#pragma unroll
    for (int b = 0; b < 2; ++b) acc[a][b] = (f32x4){0.f, 0.f, 0.f, 0.f};

#pragma unroll 1
  for (int s = 0; s < 32; ++s) {
    int ks = s >> 2, j = s & 3;
    if (j == 0) {                      // A staged once per ks, reused 4x
#pragma unroll
      for (int q = 0; q < 4; ++q)
        __builtin_amdgcn_global_load_lds(
            (const __attribute__((address_space(1))) void*)(aSrc + (ks << 6) + soffA[q]),
            (__attribute__((address_space(3))) void*)((char*)aB + (q << 12) + tid * 16),
            16, 0, 0);
    }
    {
      int e = (j == 0) ? e0 : (j == 1) ? e1 : (j == 2) ? 8 : 9;
      const ushort_t* b = bSrc + ((size_t)e << 18) + (ks << 6);
#pragma unroll
      for (int q = 0; q < 2; ++q)
        __builtin_amdgcn_global_load_lds(
            (const __attribute__((address_space(1))) void*)(b + soffB[q]),
            (__attribute__((address_space(3))) void*)((char*)bB + (q << 12) + tid * 16),
            16, 0, 0);
    }
    __syncthreads();                   // drain stage(s) (+ meta on s=0)

#pragma unroll
    for (int ksl = 0; ksl < 2; ++ksl) {
      u32x4 af[4], bf[2];
#pragma unroll
      for (int i = 0; i < 4; ++i) af[i] = *(const u32x4*)((const char*)aB + aRd[i][ksl]);
#pragma unroll
      for (int i = 0; i < 2; ++i) bf[i] = *(const u32x4*)((const char*)bB + bRd[i][ksl]);
#pragma unroll
      for (int rb = 0; rb < 4; ++rb) {
        short8 a8 = __builtin_bit_cast(short8, af[rb]);
#pragma unroll
        for (int cb = 0; cb < 2; ++cb) {
          short8 b8 = __builtin_bit_cast(short8, bf[cb]);
          acc[rb][cb] = __builtin_amdgcn_mfma_f32_16x16x32_bf16(a8, b8, acc[rb][cb], 0, 0, 0);
        }
      }
    }

    if (s < 31) {                      // telescope boundary: acc *= w_j/w_{j+1}
#pragma unroll
      for (int rb = 0; rb < 4; ++rb) {
        int rl = wr * 64 + rb * 16 + ((lane >> 4) << 2);
        f32x4 rv = *(const f32x4*)&wRT[(j << 7) + rl];
#pragma unroll
        for (int cb = 0; cb < 2; ++cb) acc[rb][cb] *= rv;
      }
    }
    __syncthreads();                   // WAR: nobody overwrites LDS early
  }

  // epilogue: v = acc*w3 + sum_j w_j[row]*b_ej[col]; predicated scatter by token
#pragma unroll
  for (int rb = 0; rb < 4; ++rb) {
    int rl = wr * 64 + rb * 16 + ((lane >> 4) << 2);
    f32x4 wv[4];
#pragma unroll
    for (int j = 0; j < 4; ++j) wv[j] = *(const f32x4*)&wLT[(j << 7) + rl];
    int tok[4]; bool pr[4];
#pragma unroll
    for (int q = 0; q < 4; ++q) {
      int rs = rl + q; pr[q] = rs < cl;
      tok[q] = pr[q] ? (int)idx[base + rs] : 0;
    }
#pragma unroll
    for (int cb = 0; cb < 2; ++cb) {
      int cloc = wc * 32 + cb * 16 + (lane & 15);
      f32x4 v = acc[rb][cb] * wv[3];
#pragma unroll
      for (int j = 0; j < 4; ++j) v += wv[j] * bL[(j << 6) + cloc];
#pragma unroll
      for (int q = 0; q < 4; ++q)
        if (pr[q]) out[(size_t)tok[q] * DIM + tcol + cloc] = v[q];
    }
  }
}

extern "C" void kernel_launch(void* const* d_in, const int* in_sizes, int n_in,
                              void* d_out, int out_size, void* d_ws, size_t ws_size,
                              hipStream_t stream) {
  (void)in_sizes; (void)n_in; (void)out_size; (void)ws_size;
  const float* x   = (const float*)d_in[0];
  const float* srl = (const float*)d_in[1];
  const float* shl = (const float*)d_in[2];
  const float* sW  = (const float*)d_in[3];
  const float* sb  = (const float*)d_in[4];
  const float* hW  = (const float*)d_in[5];
  const float* hb  = (const float*)d_in[6];
  float* out = (float*)d_out;

  // workspace layout (~22.6 MB)
  char* ws = (char*)d_ws;
  float*    w4     = (float*)ws;     ws += TOK * 4 * 4;              // 256 KB
  int*      pairid = (int*)ws;       ws += TOK * 4;                  // 64 KB
  ushort_t* idx    = (ushort_t*)ws;  ws += (TOK + 128) * 2 + 256;    // ~33 KB
  int*      cntp   = (int*)ws;       ws += NPAIR * 4;
  int*      offp   = (int*)ws;       ws += NPAIR * 4;
  int*      curp   = (int*)ws;       ws += NPAIR * 4;
  int*      tsp    = (int*)ws;       ws += (NPAIR + 1) * 4;
  int*      tinfo  = (int*)ws;       ws += MAXTILES * 4 + 208;       // pad to 256B
  ushort_t* xg     = (ushort_t*)ws;  ws += (size_t)(TOK + 128) * DIM * 2;  // 16.9 MB
  ushort_t* wt     = (ushort_t*)ws;                                   // 5.25 MB

  hipMemsetAsync(cntp, 0, NPAIR * sizeof(int), stream);
  dim3 tb(32, 32, 1), tg(16, 16, 11);
  k_prep<<<tg, tb, 0, stream>>>(sW, hW, wt, srl, shl, w4, pairid, cntp);
  k_scan<<<1, 64, 0, stream>>>(cntp, offp, curp, tsp, tinfo, idx);
  k_fill<<<TOK / 256, 256, 0, stream>>>(pairid, curp, idx);
  k_gather<<<(TOK + 128) / 4, 256, 0, stream>>>(x, idx, xg);
  k_moe<<<MAXTILES * 8, 256, 0, stream>>>(xg, wt, w4, idx, offp, cntp, tsp, tinfo,
                                          sb, hb, out);
}